// Round 2
// baseline (263.070 us; speedup 1.0000x reference)
//
#include <hip/hip_runtime.h>
#include <hip/hip_fp16.h>

#define HDIM 256
#define MS 16
#define LDAK 264   // 256 + 8 halves pad
#define CSTRIDE (MS * LDAK * 2)   // 8448 B per channel block

typedef _Float16 half8 __attribute__((ext_vector_type(8)));
typedef _Float16 half4 __attribute__((ext_vector_type(4)));
typedef _Float16 half2v __attribute__((ext_vector_type(2)));
typedef float f32x4 __attribute__((ext_vector_type(4)));

__device__ __forceinline__ float fast_tanh(float x) {
    float e = __expf(2.0f * x);
    return 1.0f - 2.0f * __builtin_amdgcn_rcpf(e + 1.0f);
}

__device__ __forceinline__ half4 cvt4(float a, float b, float c, float d) {
    half2v lo = __builtin_bit_cast(half2v, __builtin_amdgcn_cvt_pkrtz(a, b));
    half2v hi = __builtin_bit_cast(half2v, __builtin_amdgcn_cvt_pkrtz(c, d));
    half4 r; r[0] = lo[0]; r[1] = lo[1]; r[2] = hi[0]; r[3] = hi[1];
    return r;
}

// Barrier draining only LDS (lgkmcnt) — global wf prefetches stay in flight.
__device__ __forceinline__ void barrier_lds() {
    asm volatile("s_waitcnt lgkmcnt(0)\n\ts_barrier" ::: "memory");
}

// Pack W1,W2,W3 (fp32 [256][256]) into f16 frag layout Wp[g*8192 + frag].
__global__ __launch_bounds__(256) void pack_weights(const float* __restrict__ W1,
                                                    const float* __restrict__ W2,
                                                    const float* __restrict__ W3,
                                                    _Float16* __restrict__ out) {
    int tid = blockIdx.x * 256 + threadIdx.x;  // 0..24575
    int l = tid >> 13;
    int idx = tid & 8191;   // kg*256 + n
    int kg = idx >> 8;
    int n = idx & 255;
    const float* W = (l == 0) ? W1 : (l == 1) ? W2 : W3;
    half8 v;
    #pragma unroll
    for (int j = 0; j < 8; ++j) v[j] = (_Float16)W[(kg * 8 + j) * 256 + n];
    *(half8*)(out + l * 65536 + kg * 2048 + n * 8) = v;
}

// Two-group software pipeline: 512 threads, 8 waves, 32 samples/block.
// Every window pairs MFMA of one group with elementwise of the other, in
// DISTINCT LDS arrays so the scheduler may interleave freely.
__global__ __launch_bounds__(512, 2)
void pinn_fused(const float* __restrict__ x,
                const float* __restrict__ W0,
                const float* __restrict__ b0,
                const float* __restrict__ b1,
                const float* __restrict__ b2,
                const float* __restrict__ b3,
                const float* __restrict__ Wout,
                const float* __restrict__ bout,
                const _Float16* __restrict__ Wp,
                float* __restrict__ out) {
    __shared__ __align__(16) _Float16 AbA[7 * MS][LDAK];   // group A activations/jets
    __shared__ __align__(16) _Float16 AbB[7 * MS][LDAK];   // group B
    __shared__ float part[2][8 * 7 * MS];                  // per-wave output partials

    const int tid  = threadIdx.x;
    const int lane = tid & 63;
    const int wid  = tid >> 6;        // wave 0..7 -> n-strip base wid*32
    const int qd   = lane >> 4;
    const int n15  = lane & 15;
    const int base = blockIdx.x * (2 * MS);
    const int nw   = wid * 32 + n15;

    const int voff0 = (qd * 256 + nw) * 8;                 // Wp frag base (halves)
    const int abase = (n15 * LDAK + qd * 8) * 2;           // af read base (bytes)
    const int sbase = (n15 * LDAK + wid * 32 + qd * 4) * 2; // elem write base (bytes)

    half8 wf[3][2];   // rolling W pipeline; 2 n-frags per step (32-col strip)

// flat step J = window*8 + s; window w: layer = w>>1 (A/B alternate), g = layer*8 + s
#define PREF(J) do { \
    if ((J) < 48) { \
        const int g_ = (((J) >> 4) * 8) + ((J) & 7); \
        wf[(J) % 3][0] = *(const half8*)(Wp + g_ * 8192 + voff0); \
        wf[(J) % 3][1] = *(const half8*)(Wp + g_ * 8192 + voff0 + 128); \
    } \
} while (0)

#define KSTEP(ACC, AB, J) do { \
    const int s_ = (J) & 7; \
    PREF((J) + 2); \
    half8 af_[7]; \
    _Pragma("unroll") \
    for (int c_ = 0; c_ < 7; ++c_) \
        af_[c_] = *(const half8*)((const char*)AB + abase + c_ * CSTRIDE + s_ * 64); \
    _Pragma("unroll") \
    for (int c_ = 0; c_ < 7; ++c_) \
        _Pragma("unroll") \
        for (int t_ = 0; t_ < 2; ++t_) \
            ACC[c_][t_] = __builtin_amdgcn_mfma_f32_16x16x32_f16(wf[(J) % 3][t_], af_[c_], ACC[c_][t_], 0, 0, 0); \
} while (0)

// lane holds Z[m = n15][n = wid*32 + T*16 + qd*4 + r], r=0..3
#define ELEMW(ACC, AB, BB, T) do { \
    const int ncol_ = wid * 32 + (T) * 16 + qd * 4; \
    f32x4 bv_ = *(const f32x4*)((BB) + ncol_); \
    float tv_[4], gj_[3][4], sj_[3][4]; \
    _Pragma("unroll") \
    for (int r_ = 0; r_ < 4; ++r_) { \
        float zv_ = ACC[0][T][r_] + bv_[r_]; \
        tv_[r_] = fast_tanh(zv_); \
        float dd_ = 1.f - tv_[r_] * tv_[r_]; \
        float c2_ = -2.f * tv_[r_] * dd_; \
        _Pragma("unroll") \
        for (int i_ = 0; i_ < 3; ++i_) { \
            float zg_ = ACC[1 + i_][T][r_]; \
            float zs_ = ACC[4 + i_][T][r_]; \
            gj_[i_][r_] = dd_ * zg_; \
            sj_[i_][r_] = dd_ * zs_ + c2_ * zg_ * zg_; \
        } \
    } \
    char* sb_ = (char*)AB + sbase; \
    *(half4*)(sb_ + 0 * CSTRIDE + (T) * 32) = cvt4(tv_[0], tv_[1], tv_[2], tv_[3]); \
    _Pragma("unroll") \
    for (int i_ = 0; i_ < 3; ++i_) { \
        *(half4*)(sb_ + (1 + i_) * CSTRIDE + (T) * 32) = \
            cvt4(gj_[i_][0], gj_[i_][1], gj_[i_][2], gj_[i_][3]); \
        *(half4*)(sb_ + (4 + i_) * CSTRIDE + (T) * 32) = \
            cvt4(sj_[i_][0], sj_[i_][1], sj_[i_][2], sj_[i_][3]); \
    } \
} while (0)

// layer 0: each of 512 threads computes one 8-col chunk for its sample m0
#define L0G(AB, X0, X1, X2) do { \
    half8 h_[7]; \
    _Pragma("unroll") \
    for (int r_ = 0; r_ < 8; ++r_) { \
        const float w0_ = w0v[r_ >> 2][r_ & 3]; \
        const float w1_ = w1v[r_ >> 2][r_ & 3]; \
        const float w2_ = w2v[r_ >> 2][r_ & 3]; \
        float z_  = (X0) * w0_ + (X1) * w1_ + (X2) * w2_ + b0v[r_ >> 2][r_ & 3]; \
        float tv_ = fast_tanh(z_); \
        float dd_ = 1.f - tv_ * tv_; \
        float c2_ = -2.f * tv_ * dd_; \
        h_[0][r_] = (_Float16)tv_; \
        h_[1][r_] = (_Float16)(dd_ * w0_); \
        h_[2][r_] = (_Float16)(dd_ * w1_); \
        h_[3][r_] = (_Float16)(dd_ * w2_); \
        h_[4][r_] = (_Float16)(c2_ * w0_ * w0_); \
        h_[5][r_] = (_Float16)(c2_ * w1_ * w1_); \
        h_[6][r_] = (_Float16)(c2_ * w2_ * w2_); \
    } \
    _Pragma("unroll") \
    for (int c_ = 0; c_ < 7; ++c_) \
        *(half8*)&AB[c_ * MS + m0][n0] = h_[c_]; \
} while (0)

#define OUTG(ACC, G) do { \
    float p_[7] = {0.f, 0.f, 0.f, 0.f, 0.f, 0.f, 0.f}; \
    _Pragma("unroll") \
    for (int t_ = 0; t_ < 2; ++t_) { \
        const int ncol_ = wid * 32 + t_ * 16 + qd * 4; \
        f32x4 bv_ = *(const f32x4*)(b3 + ncol_); \
        f32x4 wv_ = *(const f32x4*)(Wout + ncol_); \
        _Pragma("unroll") \
        for (int r_ = 0; r_ < 4; ++r_) { \
            float zv_ = ACC[0][t_][r_] + bv_[r_]; \
            float tv_ = fast_tanh(zv_); \
            float dd_ = 1.f - tv_ * tv_; \
            float c2_ = -2.f * tv_ * dd_; \
            p_[0] += tv_ * wv_[r_]; \
            _Pragma("unroll") \
            for (int i_ = 0; i_ < 3; ++i_) { \
                float zg_ = ACC[1 + i_][t_][r_]; \
                float zs_ = ACC[4 + i_][t_][r_]; \
                p_[1 + i_] += (dd_ * zg_) * wv_[r_]; \
                p_[4 + i_] += (dd_ * zs_ + c2_ * zg_ * zg_) * wv_[r_]; \
            } \
        } \
    } \
    _Pragma("unroll") \
    for (int c_ = 0; c_ < 7; ++c_) { \
        p_[c_] += __shfl_xor(p_[c_], 16, 64); \
        p_[c_] += __shfl_xor(p_[c_], 32, 64); \
    } \
    if (lane < 16) { \
        _Pragma("unroll") \
        for (int c_ = 0; c_ < 7; ++c_) \
            part[G][(wid * 7 + c_) * MS + lane] = p_[c_]; \
    } \
} while (0)

#define ZACC(A_) do { \
    _Pragma("unroll") \
    for (int c_ = 0; c_ < 7; ++c_) \
        _Pragma("unroll") \
        for (int t_ = 0; t_ < 2; ++t_) A_[c_][t_] = (f32x4){0.f, 0.f, 0.f, 0.f}; \
} while (0)

    // per-thread sample coords for both groups
    const int m0 = tid & 15;
    const int n0 = (tid >> 4) * 8;    // this thread's layer-0 column chunk
    const float xa0 = x[(base + m0) * 3 + 0];
    const float xa1 = x[(base + m0) * 3 + 1];
    const float xa2 = x[(base + m0) * 3 + 2];
    const float xb0 = x[(base + MS + m0) * 3 + 0];
    const float xb1 = x[(base + MS + m0) * 3 + 1];
    const float xb2 = x[(base + MS + m0) * 3 + 2];

    PREF(0);
    PREF(1);

    // W0 column block (shared by both groups' layer 0)
    f32x4 w0v[2], w1v[2], w2v[2], b0v[2];
    w0v[0] = *(const f32x4*)(W0 + n0);            w0v[1] = *(const f32x4*)(W0 + n0 + 4);
    w1v[0] = *(const f32x4*)(W0 + HDIM + n0);     w1v[1] = *(const f32x4*)(W0 + HDIM + n0 + 4);
    w2v[0] = *(const f32x4*)(W0 + 2 * HDIM + n0); w2v[1] = *(const f32x4*)(W0 + 2 * HDIM + n0 + 4);
    b0v[0] = *(const f32x4*)(b0 + n0);            b0v[1] = *(const f32x4*)(b0 + n0 + 4);

    f32x4 accA[7][2], accB[7][2];

    // T0: L0(A)
    L0G(AbA, xa0, xa1, xa2);
    barrier_lds();

    // T1: K1(A) || L0(B)
    ZACC(accA);
    KSTEP(accA, AbA, 0);
    KSTEP(accA, AbA, 1);
    L0G(AbB, xb0, xb1, xb2);
    KSTEP(accA, AbA, 2); KSTEP(accA, AbA, 3); KSTEP(accA, AbA, 4);
    KSTEP(accA, AbA, 5); KSTEP(accA, AbA, 6); KSTEP(accA, AbA, 7);
    barrier_lds();

    // T2: K1(B) || elem1(A)
    ZACC(accB);
    KSTEP(accB, AbB, 8);
    ELEMW(accA, AbA, b1, 0);
    KSTEP(accB, AbB, 9); KSTEP(accB, AbB, 10); KSTEP(accB, AbB, 11);
    ELEMW(accA, AbA, b1, 1);
    KSTEP(accB, AbB, 12); KSTEP(accB, AbB, 13); KSTEP(accB, AbB, 14); KSTEP(accB, AbB, 15);
    barrier_lds();

    // T3: K2(A) || elem1(B)
    ZACC(accA);
    KSTEP(accA, AbA, 16);
    ELEMW(accB, AbB, b1, 0);
    KSTEP(accA, AbA, 17); KSTEP(accA, AbA, 18); KSTEP(accA, AbA, 19);
    ELEMW(accB, AbB, b1, 1);
    KSTEP(accA, AbA, 20); KSTEP(accA, AbA, 21); KSTEP(accA, AbA, 22); KSTEP(accA, AbA, 23);
    barrier_lds();

    // T4: K2(B) || elem2(A)
    ZACC(accB);
    KSTEP(accB, AbB, 24);
    ELEMW(accA, AbA, b2, 0);
    KSTEP(accB, AbB, 25); KSTEP(accB, AbB, 26); KSTEP(accB, AbB, 27);
    ELEMW(accA, AbA, b2, 1);
    KSTEP(accB, AbB, 28); KSTEP(accB, AbB, 29); KSTEP(accB, AbB, 30); KSTEP(accB, AbB, 31);
    barrier_lds();

    // T5: K3(A) || elem2(B)
    ZACC(accA);
    KSTEP(accA, AbA, 32);
    ELEMW(accB, AbB, b2, 0);
    KSTEP(accA, AbA, 33); KSTEP(accA, AbA, 34); KSTEP(accA, AbA, 35);
    ELEMW(accB, AbB, b2, 1);
    KSTEP(accA, AbA, 36); KSTEP(accA, AbA, 37); KSTEP(accA, AbA, 38); KSTEP(accA, AbA, 39);
    barrier_lds();

    // T6: K3(B) || out(A); then out(B) (regs + part only; no Abuf deps)
    ZACC(accB);
    KSTEP(accB, AbB, 40); KSTEP(accB, AbB, 41);
    OUTG(accA, 0);
    KSTEP(accB, AbB, 42); KSTEP(accB, AbB, 43); KSTEP(accB, AbB, 44);
    KSTEP(accB, AbB, 45); KSTEP(accB, AbB, 46); KSTEP(accB, AbB, 47);
    OUTG(accB, 1);
    barrier_lds();

    // final reduce across the 8 waves; store [B,7] for both groups
    if ((tid & 255) < 112) {
        const int g = tid >> 8;          // 0: tid<112, 1: 256<=tid<368
        const int c = (tid & 255) >> 4;
        const int m = tid & 15;
        float v = 0.f;
        #pragma unroll
        for (int w = 0; w < 8; ++w) v += part[g][(w * 7 + c) * MS + m];
        if (c == 0) v += bout[0];
        out[(base + g * MS + m) * 7 + c] = v;
    }

#undef PREF
#undef KSTEP
#undef ELEMW
#undef L0G
#undef OUTG
#undef ZACC
}

extern "C" void kernel_launch(void* const* d_in, const int* in_sizes, int n_in,
                              void* d_out, int out_size, void* d_ws, size_t ws_size,
                              hipStream_t stream) {
    const float* xp   = (const float*)d_in[0];
    const float* W0   = (const float*)d_in[1];
    const float* b0   = (const float*)d_in[2];
    const float* W1   = (const float*)d_in[3];
    const float* b1   = (const float*)d_in[4];
    const float* W2   = (const float*)d_in[5];
    const float* b2   = (const float*)d_in[6];
    const float* W3   = (const float*)d_in[7];
    const float* b3   = (const float*)d_in[8];
    const float* Wout = (const float*)d_in[9];
    const float* bout = (const float*)d_in[10];
    _Float16* Wp = (_Float16*)d_ws;  // 3 * 65536 halves = 384 KB

    pack_weights<<<96, 256, 0, stream>>>(W1, W2, W3, Wp);
    pinn_fused<<<65536 / (2 * MS), 512, 0, stream>>>(xp, W0, b0, b1, b2, b3, Wout, bout,
                                                     Wp, (float*)d_out);
}

// Round 3
// 249.141 us; speedup vs baseline: 1.0559x; 1.0559x over previous
//
#include <hip/hip_runtime.h>
#include <hip/hip_fp16.h>

#define HDIM 256
#define MS 16
#define LDAK 264   // 256 + 8 halves pad; measured-balanced for b128 reads & b64 writes
#define CSTRIDE (MS * LDAK * 2)   // 8448 B per channel block

typedef _Float16 half8 __attribute__((ext_vector_type(8)));
typedef _Float16 half4 __attribute__((ext_vector_type(4)));
typedef _Float16 half2v __attribute__((ext_vector_type(2)));
typedef float f32x4 __attribute__((ext_vector_type(4)));

__device__ __forceinline__ float fast_tanh(float x) {
    // tanh(x) = 1 - 2/(e^{2x}+1); v_exp-based, graceful at +-inf
    float e = __expf(2.0f * x);
    return 1.0f - 2.0f * __builtin_amdgcn_rcpf(e + 1.0f);
}

__device__ __forceinline__ half4 cvt4(float a, float b, float c, float d) {
    half2v lo = __builtin_bit_cast(half2v, __builtin_amdgcn_cvt_pkrtz(a, b));
    half2v hi = __builtin_bit_cast(half2v, __builtin_amdgcn_cvt_pkrtz(c, d));
    half4 r; r[0] = lo[0]; r[1] = lo[1]; r[2] = hi[0]; r[3] = hi[1];
    return r;
}

// Workgroup barrier draining only LDS (lgkmcnt) — leaves in-flight global
// wf prefetches (vmcnt) pending across the barrier.
__device__ __forceinline__ void barrier_lds() {
    asm volatile("s_waitcnt lgkmcnt(0)\n\ts_barrier" ::: "memory");
}

// Pack W1,W2,W3 (fp32 [256][256]) into f16 frag layout Wp[g*8192 + frag], g = flat
// K-step l*8+s; within a step: kg-sub*2048 + n*8 + (k&7).
__global__ __launch_bounds__(256) void pack_weights(const float* __restrict__ W1,
                                                    const float* __restrict__ W2,
                                                    const float* __restrict__ W3,
                                                    _Float16* __restrict__ out) {
    int tid = blockIdx.x * 256 + threadIdx.x;  // 0..24575
    int l = tid >> 13;
    int idx = tid & 8191;   // kg*256 + n
    int kg = idx >> 8;      // k-group of 8
    int n = idx & 255;
    const float* W = (l == 0) ? W1 : (l == 1) ? W2 : W3;
    half8 v;
    #pragma unroll
    for (int j = 0; j < 8; ++j) v[j] = (_Float16)W[(kg * 8 + j) * 256 + n];
    *(half8*)(out + l * 65536 + kg * 2048 + n * 8) = v;
}

__global__ __launch_bounds__(256, 2)
void pinn_fused(const float* __restrict__ x,
                const float* __restrict__ W0,
                const float* __restrict__ b0,
                const float* __restrict__ b1,
                const float* __restrict__ b2,
                const float* __restrict__ b3,
                const float* __restrict__ Wout,
                const float* __restrict__ bout,
                const _Float16* __restrict__ Wp,
                float* __restrict__ out) {
    // A: stacked [7 channels x 16 samples] rows x 256 k, f16, pad-264
    __shared__ __align__(16) _Float16 Abuf[7 * MS][LDAK];
    __shared__ float part[4 * 7 * MS];   // per-wave output partials (1792 B)

    const int tid  = threadIdx.x;
    const int lane = tid & 63;
    const int wid  = tid >> 6;        // wave 0..3 -> n-strip base wid*64
    const int qd   = lane >> 4;
    const int n15  = lane & 15;
    const int base = blockIdx.x * MS;
    const int nw   = wid * 64 + n15;

    // Linear W addressing: frag(g,t) at Wp + g*8192 + voff0 + t*128 (halves).
    const int voff0 = (qd * 256 + nw) * 8;

    const char* Ab = (const char*)Abuf;
    const int abase = (n15 * LDAK + qd * 8) * 2;                 // read base (bytes)
    char* Sb = (char*)Abuf;
    const int sbase = (n15 * LDAK + wid * 64 + qd * 4) * 2;      // write base (bytes)

    // 3-deep rolling W-fragment pipeline over flat step g = l*8 + s.
    half8 wf[3][4];

#define PREF(G) do { \
    if ((G) < 24) { \
        _Pragma("unroll") \
        for (int t_ = 0; t_ < 4; ++t_) \
            wf[(G) % 3][t_] = *(const half8*)(Wp + (G) * 8192 + voff0 + t_ * 128); \
    } \
} while (0)

// Load the 7 per-channel A fragments of K-step S into register buffer AF.
#define LDAF(AF, S) do { \
    _Pragma("unroll") \
    for (int c_ = 0; c_ < 7; ++c_) \
        AF[c_] = *(const half8*)(Ab + abase + c_ * CSTRIDE + (S) * 64); \
} while (0)

// 28 MFMAs of flat step G consuming AF (loaded one step earlier), plus
// wf prefetch for G+2. setprio(1) keeps the MFMA wave favored on the CU
// scheduler vs the co-resident block's memory-phase waves.
#define MMS(ACC, AF, G) do { \
    PREF((G) + 2); \
    __builtin_amdgcn_s_setprio(1); \
    _Pragma("unroll") \
    for (int c_ = 0; c_ < 7; ++c_) \
        _Pragma("unroll") \
        for (int t_ = 0; t_ < 4; ++t_) \
            ACC[c_][t_] = __builtin_amdgcn_mfma_f32_16x16x32_f16(wf[(G) % 3][t_], AF[c_], ACC[c_][t_], 0, 0, 0); \
    __builtin_amdgcn_s_setprio(0); \
} while (0)

// Software-pipelined 8-step K-loop: af double-buffered in registers, each
// LDAF issued one step ahead of its consuming MFMA cluster so LDS latency
// hides under ~540cy of MFMA issue. G0 = 8*layer.
#define KLOOP(ACC, G0) do { \
    half8 afX[7], afY[7]; \
    LDAF(afX, 0); \
    LDAF(afY, 1); \
    MMS(ACC, afX, (G0) + 0); \
    LDAF(afX, 2); \
    MMS(ACC, afY, (G0) + 1); \
    LDAF(afY, 3); \
    MMS(ACC, afX, (G0) + 2); \
    LDAF(afX, 4); \
    MMS(ACC, afY, (G0) + 3); \
    LDAF(afY, 5); \
    MMS(ACC, afX, (G0) + 4); \
    LDAF(afX, 6); \
    MMS(ACC, afY, (G0) + 5); \
    LDAF(afY, 7); \
    MMS(ACC, afX, (G0) + 6); \
    MMS(ACC, afY, (G0) + 7); \
} while (0)

#define ZACC(A_) do { \
    _Pragma("unroll") \
    for (int c_ = 0; c_ < 7; ++c_) \
        _Pragma("unroll") \
        for (int t_ = 0; t_ < 4; ++t_) A_[c_][t_] = (f32x4){0.f, 0.f, 0.f, 0.f}; \
} while (0)

    // initial W prefetch: g=0 and g=1
    PREF(0);
    PREF(1);

    // ---------------- layer 0: 3 -> 256, jets analytic; vectorized loads ----------------
    {
        const int m  = tid & 15;
        const int nb = (tid >> 4) * 16;   // 16 consecutive n per thread, 2 chunks
        const float x0 = x[(base + m) * 3 + 0];
        const float x1 = x[(base + m) * 3 + 1];
        const float x2 = x[(base + m) * 3 + 2];
        #pragma unroll
        for (int ch = 0; ch < 2; ++ch) {
            const int n0 = nb + ch * 8;
            f32x4 w0v[2], w1v[2], w2v[2], bv[2];
            w0v[0] = *(const f32x4*)(W0 + n0);            w0v[1] = *(const f32x4*)(W0 + n0 + 4);
            w1v[0] = *(const f32x4*)(W0 + HDIM + n0);     w1v[1] = *(const f32x4*)(W0 + HDIM + n0 + 4);
            w2v[0] = *(const f32x4*)(W0 + 2 * HDIM + n0); w2v[1] = *(const f32x4*)(W0 + 2 * HDIM + n0 + 4);
            bv[0]  = *(const f32x4*)(b0 + n0);            bv[1]  = *(const f32x4*)(b0 + n0 + 4);
            half8 h[7];
            #pragma unroll
            for (int r = 0; r < 8; ++r) {
                const float w0 = w0v[r >> 2][r & 3];
                const float w1 = w1v[r >> 2][r & 3];
                const float w2 = w2v[r >> 2][r & 3];
                float z  = x0 * w0 + x1 * w1 + x2 * w2 + bv[r >> 2][r & 3];
                float tv = fast_tanh(z);
                float dd = 1.f - tv * tv;
                float c2 = -2.f * tv * dd;
                h[0][r] = (_Float16)tv;
                h[1][r] = (_Float16)(dd * w0);
                h[2][r] = (_Float16)(dd * w1);
                h[3][r] = (_Float16)(dd * w2);
                h[4][r] = (_Float16)(c2 * w0 * w0);
                h[5][r] = (_Float16)(c2 * w1 * w1);
                h[6][r] = (_Float16)(c2 * w2 * w2);
            }
            #pragma unroll
            for (int c = 0; c < 7; ++c)
                *(half8*)&Abuf[c * MS + m][n0] = h[c];
        }
    }
    barrier_lds();

    // ---------------- layers 1..2: pipelined MFMA + elem write-back ----------------
    #pragma unroll
    for (int l = 0; l < 2; ++l) {
        const float* bb = (l == 0) ? b1 : b2;

        f32x4 acc[7][4];
        ZACC(acc);
        KLOOP(acc, l * 8);
        barrier_lds();   // all waves done reading Abuf (lgkm only; wf stays in flight)

        // lane holds Z[m = n15][n = wid*64 + t*16 + qd*4 + r], r=0..3
        #pragma unroll
        for (int t = 0; t < 4; ++t) {
            const int ncol = wid * 64 + t * 16 + qd * 4;
            f32x4 bv = *(const f32x4*)(bb + ncol);
            float tv[4], gj[3][4], sj[3][4];
            #pragma unroll
            for (int r = 0; r < 4; ++r) {
                float zv = acc[0][t][r] + bv[r];
                tv[r] = fast_tanh(zv);
                float dd = 1.f - tv[r] * tv[r];
                float c2 = -2.f * tv[r] * dd;
                #pragma unroll
                for (int i = 0; i < 3; ++i) {
                    float zg = acc[1 + i][t][r];
                    float zs = acc[4 + i][t][r];
                    gj[i][r] = dd * zg;
                    sj[i][r] = dd * zs + c2 * zg * zg;
                }
            }
            *(half4*)(Sb + sbase + 0 * CSTRIDE + t * 32) = cvt4(tv[0], tv[1], tv[2], tv[3]);
            #pragma unroll
            for (int i = 0; i < 3; ++i) {
                *(half4*)(Sb + sbase + (1 + i) * CSTRIDE + t * 32) =
                    cvt4(gj[i][0], gj[i][1], gj[i][2], gj[i][3]);
                *(half4*)(Sb + sbase + (4 + i) * CSTRIDE + t * 32) =
                    cvt4(sj[i][0], sj[i][1], sj[i][2], sj[i][3]);
            }
        }
        barrier_lds();   // writes visible before next K
    }

    // ---------------- layer 3: K-loop + FUSED elem/output (no Abuf writes) ----------------
    {
        f32x4 acc[7][4];
        ZACC(acc);
        KLOOP(acc, 16);
        // No post-K barrier: fused elem touches only registers + `part`.

        // per-lane partial dot with Wout over this lane's 16 columns (fp32 path)
        float p[7] = {0.f, 0.f, 0.f, 0.f, 0.f, 0.f, 0.f};
        #pragma unroll
        for (int t = 0; t < 4; ++t) {
            const int ncol = wid * 64 + t * 16 + qd * 4;
            f32x4 bv = *(const f32x4*)(b3 + ncol);
            f32x4 wv = *(const f32x4*)(Wout + ncol);
            #pragma unroll
            for (int r = 0; r < 4; ++r) {
                float zv = acc[0][t][r] + bv[r];
                float tv = fast_tanh(zv);
                float dd = 1.f - tv * tv;
                float c2 = -2.f * tv * dd;
                p[0] += tv * wv[r];
                #pragma unroll
                for (int i = 0; i < 3; ++i) {
                    float zg = acc[1 + i][t][r];
                    float zs = acc[4 + i][t][r];
                    p[1 + i] += (dd * zg) * wv[r];
                    p[4 + i] += (dd * zs + c2 * zg * zg) * wv[r];
                }
            }
        }
        // reduce over the 4 qd lanes sharing sample n15
        #pragma unroll
        for (int c = 0; c < 7; ++c) {
            p[c] += __shfl_xor(p[c], 16, 64);
            p[c] += __shfl_xor(p[c], 32, 64);
        }
        if (lane < 16) {
            #pragma unroll
            for (int c = 0; c < 7; ++c)
                part[(wid * 7 + c) * MS + lane] = p[c];
        }
    }
    barrier_lds();

    // ---------------- final reduce across the 4 waves; store [B,7] ----------------
    if (tid < 7 * MS) {
        const int c = tid >> 4;   // channel
        const int m = tid & 15;   // sample
        float v = part[(0 * 7 + c) * MS + m] + part[(1 * 7 + c) * MS + m] +
                  part[(2 * 7 + c) * MS + m] + part[(3 * 7 + c) * MS + m];
        if (c == 0) v += bout[0];
        out[(base + m) * 7 + c] = v;
    }

#undef PREF
#undef LDAF
#undef MMS
#undef KLOOP
#undef ZACC
}

extern "C" void kernel_launch(void* const* d_in, const int* in_sizes, int n_in,
                              void* d_out, int out_size, void* d_ws, size_t ws_size,
                              hipStream_t stream) {
    const float* xp   = (const float*)d_in[0];
    const float* W0   = (const float*)d_in[1];
    const float* b0   = (const float*)d_in[2];
    const float* W1   = (const float*)d_in[3];
    const float* b1   = (const float*)d_in[4];
    const float* W2   = (const float*)d_in[5];
    const float* b2   = (const float*)d_in[6];
    const float* W3   = (const float*)d_in[7];
    const float* b3   = (const float*)d_in[8];
    const float* Wout = (const float*)d_in[9];
    const float* bout = (const float*)d_in[10];
    _Float16* Wp = (_Float16*)d_ws;  // 3 * 65536 halves = 384 KB

    pack_weights<<<96, 256, 0, stream>>>(W1, W2, W3, Wp);
    pinn_fused<<<65536 / MS, 256, 0, stream>>>(xp, W0, b0, b1, b2, b3, Wout, bout, Wp,
                                               (float*)d_out);
}